// Round 18
// baseline (56.866 us; speedup 1.0000x reference)
//
#include <hip/hip_runtime.h>
#include <hip/hip_bf16.h>

#define NROWS 8192
#define DIM 128

typedef short short8 __attribute__((ext_vector_type(8)));
typedef float f32x4 __attribute__((ext_vector_type(4)));
typedef unsigned short ushort4v __attribute__((ext_vector_type(4)));

__device__ __forceinline__ short8 asbf8(uint4 v) { return __builtin_bit_cast(short8, v); }

__device__ __forceinline__ unsigned cvtpk_bf16(float lo, float hi) {
  unsigned r;
  asm("v_cvt_pk_bf16_f32 %0, %1, %2" : "=v"(r) : "v"(lo), "v"(hi));
  return r;
}
// v_permlane32_swap: rows2,3 of a <-> rows0,1 of b
__device__ __forceinline__ void pl32swap(unsigned& a, unsigned& b) {
  asm("v_permlane32_swap_b32 %0, %1" : "+v"(a), "+v"(b));
}
// v_permlane16_swap: rows1,3 of a <-> rows0,2 of b
__device__ __forceinline__ void pl16swap(unsigned& a, unsigned& b) {
  asm("v_permlane16_swap_b32 %0, %1" : "+v"(a), "+v"(b));
}
// async global->LDS, 16B per lane; LDS dest must be linear (base + lane*16)
__device__ __forceinline__ void gload_lds16(const void* g, void* l) {
  __builtin_amdgcn_global_load_lds(
      (const __attribute__((address_space(1))) void*)g,
      (__attribute__((address_space(3))) void*)l, 16, 0, 0);
}

// ------------------------- one-shot f32 -> bf16 conversion (x and W) -------------------------
// Hoists the rounding out of qkv_proj's critical path. 8 floats -> 1 uint4 per thread.
#define XN8 (NROWS * DIM / 8)      // 131072
#define WN8 (384 * DIM / 8)        // 6144
__global__ __launch_bounds__(256) void cvt_bf16(
    const float* __restrict__ x, const float* __restrict__ W,
    unsigned short* __restrict__ xb, unsigned short* __restrict__ Wb)
{
  int i = blockIdx.x * 256 + threadIdx.x;
  const float4* s;
  uint4* d;
  if (i < XN8) {
    s = (const float4*)x + 2 * i;
    d = (uint4*)xb + i;
  } else {
    int k = i - XN8;
    s = (const float4*)W + 2 * k;
    d = (uint4*)Wb + k;
  }
  float4 a = s[0], b = s[1];
  *d = (uint4){cvtpk_bf16(a.x, a.y), cvtpk_bf16(a.z, a.w),
               cvtpk_bf16(b.x, b.y), cvtpk_bf16(b.z, b.w)};
}

// ------------------------- QKV projection (bf16 MFMA, 64x64 tiles) -------------------------
// out = x @ W^T + b with 16x16x32 bf16 MFMA (f32 accum). Q pre-scaled by log2(e).
// Inputs pre-converted bf16; staging via async global_load_lds with pre-swizzled
// sources (the proven attn pattern) -> no VALU/ds_write on the staging path.
// grid (128 row-tiles, 6): ct = part*2+half; part 0=Q 1=K 2=V, half = 64-col half.
__global__ __launch_bounds__(256) void qkv_proj(
    const unsigned short* __restrict__ xb, const unsigned short* __restrict__ Wb,
    const float* __restrict__ bias,
    unsigned short* __restrict__ Q, unsigned short* __restrict__ K, unsigned short* __restrict__ Vt)
{
  __shared__ uint4 sX[64 * 16];    // x tile [64 rows][128] bf16, swizzled (16 KB)
  __shared__ uint4 sW[64 * 16];    // W half [64 rows][128] bf16, swizzled (16 KB)

  const int mt = blockIdx.x;
  const int ct = blockIdx.y;
  const int part = ct >> 1, half = ct & 1;
  const int t = threadIdx.x;

  const unsigned short* xbase = xb + (size_t)mt * 64 * DIM;
  const unsigned short* wbase = Wb + (size_t)(part * 128 + half * 64) * DIM;
#pragma unroll
  for (int j = 0; j < 4; j++) {
    int p = t + 256 * j;
    int row = p >> 4, c16 = (p & 15) ^ (row & 7);
    gload_lds16(xbase + row * DIM + c16 * 8, (uint4*)sX + p);
    gload_lds16(wbase + row * DIM + c16 * 8, (uint4*)sW + p);
  }
  __syncthreads();

  const int w = t >> 6, l = t & 63;
  const int r = l & 15, g = l >> 4, rx = r & 7;

  if (part < 2) {
    // Q/K: wave w owns x-rows m = w*16 + r; cols = half*64 + ns*16 + 4g + reg.
    uint4 xf[4];
#pragma unroll
    for (int f = 0; f < 4; f++) xf[f] = sX[(w * 16 + r) * 16 + ((f * 4 + g) ^ rx)];
    unsigned short* dst = (part == 0) ? Q : K;
    const float scale = (part == 0) ? 1.44269504088896f : 1.0f;
    const int m = mt * 64 + w * 16 + r;
#pragma unroll
    for (int ns = 0; ns < 4; ns++) {
      f32x4 acc = (f32x4){0.f, 0.f, 0.f, 0.f};
#pragma unroll
      for (int f = 0; f < 4; f++) {
        uint4 af = sW[(ns * 16 + r) * 16 + ((f * 4 + g) ^ rx)];
        acc = __builtin_amdgcn_mfma_f32_16x16x32_bf16(asbf8(af), asbf8(xf[f]), acc, 0, 0, 0);
      }
      float4 bv = *(const float4*)&bias[part * 128 + half * 64 + ns * 16 + 4 * g];
      uint2 pk;
      pk.x = cvtpk_bf16((acc[0] + bv.x) * scale, (acc[1] + bv.y) * scale);
      pk.y = cvtpk_bf16((acc[2] + bv.z) * scale, (acc[3] + bv.w) * scale);
      *(uint2*)&dst[(size_t)m * DIM + half * 64 + ns * 16 + 4 * g] = pk;
    }
  } else {
    // V: wave w owns dims n = half*64 + w*16 + r; Vt[n][mt*64 + ms*16 + 4g + reg].
    uint4 xf[4][4];
#pragma unroll
    for (int ms = 0; ms < 4; ms++)
#pragma unroll
      for (int f = 0; f < 4; f++) xf[ms][f] = sX[(ms * 16 + r) * 16 + ((f * 4 + g) ^ rx)];
    const int n = half * 64 + w * 16 + r;
    uint4 wf[4];
#pragma unroll
    for (int f = 0; f < 4; f++) wf[f] = sW[(w * 16 + r) * 16 + ((f * 4 + g) ^ rx)];
    const float bv = bias[256 + n];
#pragma unroll
    for (int ms = 0; ms < 4; ms++) {
      f32x4 acc = (f32x4){0.f, 0.f, 0.f, 0.f};
#pragma unroll
      for (int f = 0; f < 4; f++)
        acc = __builtin_amdgcn_mfma_f32_16x16x32_bf16(asbf8(xf[ms][f]), asbf8(wf[f]), acc, 0, 0, 0);
      uint2 pk;
      pk.x = cvtpk_bf16(acc[0] + bv, acc[1] + bv);
      pk.y = cvtpk_bf16(acc[2] + bv, acc[3] + bv);
      *(uint2*)&Vt[(size_t)n * NROWS + mt * 64 + ms * 16 + 4 * g] = pk;
    }
  }
}

// ------------------------- flash attention (bf16 MFMA, swapped operands) -------------------------
// Proven-best kernel (rounds 7/13/14/17, ~42.3-42.9 us): 4 waves x 32 q-rows,
// KV tile 64, K+V both double-buffered (64 KB LDS), ONE barrier per iteration
// (prefetch issued at top, drained at bottom under the whole compute phase).
// No s_setprio (-15% measured, lockstep block). S=8 -> 512 blocks = exactly
// 2/CU, one scheduling round. Structural floor of this decomposition:
// ~164-reg state (64 AGPR oacc) pins 2 waves/SIMD; every occupancy-raising
// variant (rounds 8-11), fp8 V/P (15-16), and setprio (12) regressed.
__global__ __launch_bounds__(256, 2) void attn(
    const unsigned short* __restrict__ Q, const unsigned short* __restrict__ K,
    const unsigned short* __restrict__ Vt,
    unsigned short* __restrict__ Opb, float* __restrict__ Lp,
    float* __restrict__ outDirect, int kvlen)
{
  __shared__ uint4 sK[2][64 * 16];             // K tile [64][128] bf16, swizzled
  __shared__ uint4 sV[2][128 * 8];             // Vt tile [128][64] bf16, swizzled

  const int t = threadIdx.x;
  const int w = t >> 6, l = t & 63;
  const int r = l & 15, g = l >> 4;
  const int qt = blockIdx.x, sp = blockIdx.y;
  const int qbase = qt * 128 + w * 32;         // 32 q-rows per wave
  const int kb0 = sp * kvlen;
  const int rx = r & 7;

  // ---- staging geometry: slot p = j*256 + t (linear LDS dest) ----
  const unsigned short* kgp[4];
  const unsigned short* vgp[4];
#pragma unroll
  for (int j = 0; j < 4; j++) {
    int p = t + 256 * j;
    int krow = p >> 4, kc16 = (p & 15) ^ (krow & 7);
    kgp[j] = K + (size_t)(kb0 + krow) * DIM + kc16 * 8;
    int vrow = p >> 3, vd16 = (p & 7) ^ (vrow & 7);
    vgp[j] = Vt + (size_t)vrow * NROWS + kb0 + vd16 * 8;
  }

  uint4 qf[2][4];
#pragma unroll
  for (int u = 0; u < 2; u++) {
    const uint4* Qv = (const uint4*)(Q + (size_t)(qbase + u * 16 + r) * DIM);
#pragma unroll
    for (int f = 0; f < 4; f++) qf[u][f] = Qv[f * 4 + g];
  }

  float lsum[2] = {0.f, 0.f};
  f32x4 oacc[2][8];
#pragma unroll
  for (int u = 0; u < 2; u++)
#pragma unroll
    for (int dc = 0; dc < 8; dc++) oacc[u][dc] = (f32x4){0.f, 0.f, 0.f, 0.f};

  const int niter = kvlen >> 6;

  // prologue: stage tile 0 into buffer 0
#pragma unroll
  for (int j = 0; j < 4; j++) {
    gload_lds16(kgp[j], (uint4*)sK[0] + (t + 256 * j));
    gload_lds16(vgp[j], (uint4*)sV[0] + (t + 256 * j));
  }
  __syncthreads();

  int cur = 0;
  for (int it = 0; it < niter; ++it) {
    // ---- prefetch next tile into the other buffers (drained at bottom barrier) ----
    if (it + 1 < niter) {
      const size_t koff = (size_t)(it + 1) * 64 * DIM;
      const size_t voff = (size_t)(it + 1) * 64;
      const int nb = cur ^ 1;
#pragma unroll
      for (int j = 0; j < 4; j++) {
        gload_lds16(kgp[j] + koff, (uint4*)sK[nb] + (t + 256 * j));
        gload_lds16(vgp[j] + voff, (uint4*)sV[nb] + (t + 256 * j));
      }
    }

    // ---- S^T = K Q^T (swapped operands) ----
    f32x4 sacc[2][4];
#pragma unroll
    for (int u = 0; u < 2; u++)
#pragma unroll
      for (int kc = 0; kc < 4; kc++) sacc[u][kc] = (f32x4){0.f, 0.f, 0.f, 0.f};
#pragma unroll
    for (int kc = 0; kc < 4; kc++)
#pragma unroll
      for (int f = 0; f < 4; f++) {
        uint4 kf = sK[cur][(kc * 16 + r) * 16 + ((f * 4 + g) ^ rx)];
        sacc[0][kc] = __builtin_amdgcn_mfma_f32_16x16x32_bf16(asbf8(kf), asbf8(qf[0][f]), sacc[0][kc], 0, 0, 0);
        sacc[1][kc] = __builtin_amdgcn_mfma_f32_16x16x32_bf16(asbf8(kf), asbf8(qf[1][f]), sacc[1][kc], 0, 0, 0);
      }

    // ---- p = exp2(s); per-lane partial sums; pack pairs to bf16 ----
    unsigned c32[2][4][2];
#pragma unroll
    for (int u = 0; u < 2; u++)
#pragma unroll
      for (int kc = 0; kc < 4; kc++) {
        float p0 = __builtin_amdgcn_exp2f(sacc[u][kc][0]);
        float p1 = __builtin_amdgcn_exp2f(sacc[u][kc][1]);
        float p2 = __builtin_amdgcn_exp2f(sacc[u][kc][2]);
        float p3 = __builtin_amdgcn_exp2f(sacc[u][kc][3]);
        lsum[u] += (p0 + p1) + (p2 + p3);
        c32[u][kc][0] = cvtpk_bf16(p0, p1);
        c32[u][kc][1] = cvtpk_bf16(p2, p3);
      }

    // ---- redistribute P^T to B-fragment layout (pure VALU permlane swaps) ----
    uint4 bfrag[2][2];
#pragma unroll
    for (int u = 0; u < 2; u++)
#pragma unroll
      for (int ka = 0; ka < 2; ka++) {
        unsigned x0 = c32[u][2 * ka][0],     x1 = c32[u][2 * ka][1];
        unsigned y0 = c32[u][2 * ka + 1][0], y1 = c32[u][2 * ka + 1][1];
        pl32swap(x0, y0);
        pl16swap(x0, y0);
        pl32swap(x1, y1);
        pl16swap(x1, y1);
        bfrag[u][ka] = (uint4){x0, x1, y0, y1};
      }

    // ---- O^T += V^T P^T (vf shared across both q-subtiles) ----
#pragma unroll
    for (int dc = 0; dc < 8; dc++) {
      uint4 vf0 = sV[cur][(dc * 16 + r) * 8 + (g ^ rx)];
      uint4 vf1 = sV[cur][(dc * 16 + r) * 8 + ((4 + g) ^ rx)];
      oacc[0][dc] = __builtin_amdgcn_mfma_f32_16x16x32_bf16(asbf8(vf0), asbf8(bfrag[0][0]), oacc[0][dc], 0, 0, 0);
      oacc[0][dc] = __builtin_amdgcn_mfma_f32_16x16x32_bf16(asbf8(vf1), asbf8(bfrag[0][1]), oacc[0][dc], 0, 0, 0);
      oacc[1][dc] = __builtin_amdgcn_mfma_f32_16x16x32_bf16(asbf8(vf0), asbf8(bfrag[1][0]), oacc[1][dc], 0, 0, 0);
      oacc[1][dc] = __builtin_amdgcn_mfma_f32_16x16x32_bf16(asbf8(vf1), asbf8(bfrag[1][1]), oacc[1][dc], 0, 0, 0);
    }

    __syncthreads();                           // drain prefetch; free cur buffers
    cur ^= 1;
  }

  // ---- reduce row-sums across the 4 g-groups ----
#pragma unroll
  for (int u = 0; u < 2; u++) {
    float v = lsum[u];
    v += __shfl_xor(v, 16);
    v += __shfl_xor(v, 32);
    lsum[u] = v;
  }

  // ---- epilogue: lane (r,g) holds O^T[d=16dc+4g+reg][q=qbase+u*16+r] ----
  if (outDirect) {
#pragma unroll
    for (int u = 0; u < 2; u++) {
      float inv = 1.f / lsum[u];
      int q = qbase + u * 16 + r;
#pragma unroll
      for (int dc = 0; dc < 8; dc++) {
        f32x4 o = oacc[u][dc] * inv;
        *(f32x4*)&outDirect[(size_t)q * DIM + dc * 16 + 4 * g] = o;
      }
    }
  } else {
#pragma unroll
    for (int u = 0; u < 2; u++) {
      int q = qbase + u * 16 + r;
      unsigned short* po = Opb + ((size_t)sp * NROWS + q) * DIM;
#pragma unroll
      for (int dc = 0; dc < 8; dc++) {
        uint2 pk;
        pk.x = cvtpk_bf16(oacc[u][dc][0], oacc[u][dc][1]);
        pk.y = cvtpk_bf16(oacc[u][dc][2], oacc[u][dc][3]);
        *(uint2*)&po[dc * 16 + 4 * g] = pk;
      }
      if (g == 0) Lp[(size_t)sp * NROWS + q] = lsum[u];
    }
  }
}

// ------------------------- KV-split combine (bf16 partials, plain sum) -------------------------
__global__ __launch_bounds__(256) void combine(
    const unsigned short* __restrict__ Opb, const float* __restrict__ Lp,
    float* __restrict__ out, int S)
{
  int gid = blockIdx.x * 256 + threadIdx.x;    // q*32 + d4
  int q = gid >> 5, d4 = gid & 31;
  float den = 0.f, n0 = 0.f, n1 = 0.f, n2 = 0.f, n3 = 0.f;
  for (int s = 0; s < S; s++) {
    den += Lp[(size_t)s * NROWS + q];
    ushort4v h = *(const ushort4v*)&Opb[((size_t)s * NROWS + q) * DIM + d4 * 4];
    n0 += __builtin_bit_cast(float, (unsigned)h[0] << 16);
    n1 += __builtin_bit_cast(float, (unsigned)h[1] << 16);
    n2 += __builtin_bit_cast(float, (unsigned)h[2] << 16);
    n3 += __builtin_bit_cast(float, (unsigned)h[3] << 16);
  }
  float inv = 1.f / den;
  float4 o = {n0 * inv, n1 * inv, n2 * inv, n3 * inv};
  *(float4*)&out[(size_t)q * DIM + d4 * 4] = o;
}

// ------------------------- launcher -------------------------
extern "C" void kernel_launch(void* const* d_in, const int* in_sizes, int n_in,
                              void* d_out, int out_size, void* d_ws, size_t ws_size,
                              hipStream_t stream)
{
  (void)in_sizes; (void)n_in; (void)out_size;
  const float* x = (const float*)d_in[0];
  const float* W = (const float*)d_in[1];
  const float* b = (const float*)d_in[2];
  float* out = (float*)d_out;
  char* ws = (char*)d_ws;

  unsigned short* xb = (unsigned short*)ws;                 // 8192*128 bf16
  unsigned short* Wb = xb + (size_t)NROWS * DIM;            // 384*128 bf16
  unsigned short* Q  = Wb + (size_t)384 * DIM;
  unsigned short* K  = Q + (size_t)NROWS * DIM;
  unsigned short* Vt = K + (size_t)NROWS * DIM;
  const size_t headB = ((size_t)NROWS * DIM + (size_t)384 * DIM + (size_t)3 * NROWS * DIM) * 2;

  auto need = [&](int S) {
    return headB + (size_t)S * NROWS * DIM * 2 + (size_t)S * NROWS * 4;
  };
  int S; bool direct = false;
  if      (ws_size >= need(8))  S = 8;
  else if (ws_size >= need(4))  S = 4;
  else if (ws_size >= need(2))  S = 2;
  else if (ws_size >= need(1))  S = 1;
  else { S = 1; direct = true; }

  unsigned short* Opb = (unsigned short*)(ws + headB);
  float* Lp = (float*)(Opb + (size_t)S * NROWS * DIM);

  cvt_bf16<<<(XN8 + WN8) / 256, 256, 0, stream>>>(x, W, xb, Wb);
  qkv_proj<<<dim3(128, 6), 256, 0, stream>>>(xb, Wb, b, Q, K, Vt);
  attn<<<dim3(64, S), 256, 0, stream>>>(Q, K, Vt, Opb, Lp,
                                        direct ? out : nullptr, NROWS / S);
  if (!direct) combine<<<1024, 256, 0, stream>>>(Opb, Lp, out, S);
}

// Round 19
// 53.095 us; speedup vs baseline: 1.0710x; 1.0710x over previous
//
#include <hip/hip_runtime.h>
#include <hip/hip_bf16.h>

#define NROWS 8192
#define DIM 128

typedef short short8 __attribute__((ext_vector_type(8)));
typedef float f32x4 __attribute__((ext_vector_type(4)));
typedef unsigned short ushort4v __attribute__((ext_vector_type(4)));

__device__ __forceinline__ short8 asbf8(uint4 v) { return __builtin_bit_cast(short8, v); }

__device__ __forceinline__ unsigned cvtpk_bf16(float lo, float hi) {
  unsigned r;
  asm("v_cvt_pk_bf16_f32 %0, %1, %2" : "=v"(r) : "v"(lo), "v"(hi));
  return r;
}
// v_permlane32_swap: rows2,3 of a <-> rows0,1 of b
__device__ __forceinline__ void pl32swap(unsigned& a, unsigned& b) {
  asm("v_permlane32_swap_b32 %0, %1" : "+v"(a), "+v"(b));
}
// v_permlane16_swap: rows1,3 of a <-> rows0,2 of b
__device__ __forceinline__ void pl16swap(unsigned& a, unsigned& b) {
  asm("v_permlane16_swap_b32 %0, %1" : "+v"(a), "+v"(b));
}
// async global->LDS, 16B per lane; LDS dest must be linear (base + lane*16)
__device__ __forceinline__ void gload_lds16(const void* g, void* l) {
  __builtin_amdgcn_global_load_lds(
      (const __attribute__((address_space(1))) void*)g,
      (__attribute__((address_space(3))) void*)l, 16, 0, 0);
}

// ------------------------- QKV projection (bf16 MFMA, 64x64 tiles) -------------------------
// out = x @ W^T + b with 16x16x32 bf16 MFMA (f32 accum). Q pre-scaled by log2(e).
// Inline f32->bf16 staging (hoisting it to a separate kernel cost +3.2 us: extra
// launch + HBM round-trip beat the saved VALU — round 18).
// grid (128 row-tiles, 6): ct = part*2+half; part 0=Q 1=K 2=V, half = 64-col half.
__global__ __launch_bounds__(256) void qkv_proj(
    const float* __restrict__ x, const float* __restrict__ W, const float* __restrict__ bias,
    unsigned short* __restrict__ Q, unsigned short* __restrict__ K, unsigned short* __restrict__ Vt)
{
  __shared__ uint4 sX[64 * 16];    // x tile [64 rows][128] bf16, swizzled (16 KB)
  __shared__ uint4 sW[64 * 16];    // W half [64 rows][128] bf16, swizzled (16 KB)

  const int mt = blockIdx.x;
  const int ct = blockIdx.y;
  const int part = ct >> 1, half = ct & 1;
  const int t = threadIdx.x;

  const float4* xg = (const float4*)(x + (size_t)mt * 64 * DIM);
  const float4* wg = (const float4*)(W + (size_t)(part * 128 + half * 64) * DIM);
#pragma unroll
  for (int j = 0; j < 4; j++) {
    int s = t + 256 * j; int m = s >> 4, c = s & 15;
    float4 a = xg[m * 32 + 2 * c], b = xg[m * 32 + 2 * c + 1];
    sX[m * 16 + (c ^ (m & 7))] =
        (uint4){cvtpk_bf16(a.x, a.y), cvtpk_bf16(a.z, a.w), cvtpk_bf16(b.x, b.y), cvtpk_bf16(b.z, b.w)};
    float4 wa = wg[m * 32 + 2 * c], wb = wg[m * 32 + 2 * c + 1];
    sW[m * 16 + (c ^ (m & 7))] =
        (uint4){cvtpk_bf16(wa.x, wa.y), cvtpk_bf16(wa.z, wa.w), cvtpk_bf16(wb.x, wb.y), cvtpk_bf16(wb.z, wb.w)};
  }
  __syncthreads();

  const int w = t >> 6, l = t & 63;
  const int r = l & 15, g = l >> 4, rx = r & 7;

  if (part < 2) {
    // Q/K: wave w owns x-rows m = w*16 + r; cols = half*64 + ns*16 + 4g + reg.
    uint4 xf[4];
#pragma unroll
    for (int f = 0; f < 4; f++) xf[f] = sX[(w * 16 + r) * 16 + ((f * 4 + g) ^ rx)];
    unsigned short* dst = (part == 0) ? Q : K;
    const float scale = (part == 0) ? 1.44269504088896f : 1.0f;
    const int m = mt * 64 + w * 16 + r;
#pragma unroll
    for (int ns = 0; ns < 4; ns++) {
      f32x4 acc = (f32x4){0.f, 0.f, 0.f, 0.f};
#pragma unroll
      for (int f = 0; f < 4; f++) {
        uint4 af = sW[(ns * 16 + r) * 16 + ((f * 4 + g) ^ rx)];
        acc = __builtin_amdgcn_mfma_f32_16x16x32_bf16(asbf8(af), asbf8(xf[f]), acc, 0, 0, 0);
      }
      float4 bv = *(const float4*)&bias[part * 128 + half * 64 + ns * 16 + 4 * g];
      uint2 pk;
      pk.x = cvtpk_bf16((acc[0] + bv.x) * scale, (acc[1] + bv.y) * scale);
      pk.y = cvtpk_bf16((acc[2] + bv.z) * scale, (acc[3] + bv.w) * scale);
      *(uint2*)&dst[(size_t)m * DIM + half * 64 + ns * 16 + 4 * g] = pk;
    }
  } else {
    // V: wave w owns dims n = half*64 + w*16 + r; Vt[n][mt*64 + ms*16 + 4g + reg].
    uint4 xf[4][4];
#pragma unroll
    for (int ms = 0; ms < 4; ms++)
#pragma unroll
      for (int f = 0; f < 4; f++) xf[ms][f] = sX[(ms * 16 + r) * 16 + ((f * 4 + g) ^ rx)];
    const int n = half * 64 + w * 16 + r;
    uint4 wf[4];
#pragma unroll
    for (int f = 0; f < 4; f++) wf[f] = sW[(w * 16 + r) * 16 + ((f * 4 + g) ^ rx)];
    const float bv = bias[256 + n];
#pragma unroll
    for (int ms = 0; ms < 4; ms++) {
      f32x4 acc = (f32x4){0.f, 0.f, 0.f, 0.f};
#pragma unroll
      for (int f = 0; f < 4; f++)
        acc = __builtin_amdgcn_mfma_f32_16x16x32_bf16(asbf8(xf[ms][f]), asbf8(wf[f]), acc, 0, 0, 0);
      uint2 pk;
      pk.x = cvtpk_bf16(acc[0] + bv, acc[1] + bv);
      pk.y = cvtpk_bf16(acc[2] + bv, acc[3] + bv);
      *(uint2*)&Vt[(size_t)n * NROWS + mt * 64 + ms * 16 + 4 * g] = pk;
    }
  }
}

// ------------------------- flash attention (bf16 MFMA, swapped operands) -------------------------
// Proven-best kernel (rounds 7/13/14/17, ~42.3-42.9 us): 4 waves x 32 q-rows,
// KV tile 64, K+V both double-buffered (64 KB LDS), ONE barrier per iteration
// (prefetch issued at top, drained at bottom under the whole compute phase).
// No s_setprio (-15% measured, lockstep block). S=8 -> 512 blocks = exactly
// 2/CU, one scheduling round. Structural floor of this decomposition:
// ~164-reg state (64 AGPR oacc) pins 2 waves/SIMD; every occupancy-raising
// variant (rounds 8-11), fp8 V/P (15-16), setprio (12), and kernel-splitting
// (18) regressed with diagnosed causes.
__global__ __launch_bounds__(256, 2) void attn(
    const unsigned short* __restrict__ Q, const unsigned short* __restrict__ K,
    const unsigned short* __restrict__ Vt,
    unsigned short* __restrict__ Opb, float* __restrict__ Lp,
    float* __restrict__ outDirect, int kvlen)
{
  __shared__ uint4 sK[2][64 * 16];             // K tile [64][128] bf16, swizzled
  __shared__ uint4 sV[2][128 * 8];             // Vt tile [128][64] bf16, swizzled

  const int t = threadIdx.x;
  const int w = t >> 6, l = t & 63;
  const int r = l & 15, g = l >> 4;
  const int qt = blockIdx.x, sp = blockIdx.y;
  const int qbase = qt * 128 + w * 32;         // 32 q-rows per wave
  const int kb0 = sp * kvlen;
  const int rx = r & 7;

  // ---- staging geometry: slot p = j*256 + t (linear LDS dest) ----
  const unsigned short* kgp[4];
  const unsigned short* vgp[4];
#pragma unroll
  for (int j = 0; j < 4; j++) {
    int p = t + 256 * j;
    int krow = p >> 4, kc16 = (p & 15) ^ (krow & 7);
    kgp[j] = K + (size_t)(kb0 + krow) * DIM + kc16 * 8;
    int vrow = p >> 3, vd16 = (p & 7) ^ (vrow & 7);
    vgp[j] = Vt + (size_t)vrow * NROWS + kb0 + vd16 * 8;
  }

  uint4 qf[2][4];
#pragma unroll
  for (int u = 0; u < 2; u++) {
    const uint4* Qv = (const uint4*)(Q + (size_t)(qbase + u * 16 + r) * DIM);
#pragma unroll
    for (int f = 0; f < 4; f++) qf[u][f] = Qv[f * 4 + g];
  }

  float lsum[2] = {0.f, 0.f};
  f32x4 oacc[2][8];
#pragma unroll
  for (int u = 0; u < 2; u++)
#pragma unroll
    for (int dc = 0; dc < 8; dc++) oacc[u][dc] = (f32x4){0.f, 0.f, 0.f, 0.f};

  const int niter = kvlen >> 6;

  // prologue: stage tile 0 into buffer 0
#pragma unroll
  for (int j = 0; j < 4; j++) {
    gload_lds16(kgp[j], (uint4*)sK[0] + (t + 256 * j));
    gload_lds16(vgp[j], (uint4*)sV[0] + (t + 256 * j));
  }
  __syncthreads();

  int cur = 0;
  for (int it = 0; it < niter; ++it) {
    // ---- prefetch next tile into the other buffers (drained at bottom barrier) ----
    if (it + 1 < niter) {
      const size_t koff = (size_t)(it + 1) * 64 * DIM;
      const size_t voff = (size_t)(it + 1) * 64;
      const int nb = cur ^ 1;
#pragma unroll
      for (int j = 0; j < 4; j++) {
        gload_lds16(kgp[j] + koff, (uint4*)sK[nb] + (t + 256 * j));
        gload_lds16(vgp[j] + voff, (uint4*)sV[nb] + (t + 256 * j));
      }
    }

    // ---- S^T = K Q^T (swapped operands) ----
    f32x4 sacc[2][4];
#pragma unroll
    for (int u = 0; u < 2; u++)
#pragma unroll
      for (int kc = 0; kc < 4; kc++) sacc[u][kc] = (f32x4){0.f, 0.f, 0.f, 0.f};
#pragma unroll
    for (int kc = 0; kc < 4; kc++)
#pragma unroll
      for (int f = 0; f < 4; f++) {
        uint4 kf = sK[cur][(kc * 16 + r) * 16 + ((f * 4 + g) ^ rx)];
        sacc[0][kc] = __builtin_amdgcn_mfma_f32_16x16x32_bf16(asbf8(kf), asbf8(qf[0][f]), sacc[0][kc], 0, 0, 0);
        sacc[1][kc] = __builtin_amdgcn_mfma_f32_16x16x32_bf16(asbf8(kf), asbf8(qf[1][f]), sacc[1][kc], 0, 0, 0);
      }

    // ---- p = exp2(s); per-lane partial sums; pack pairs to bf16 ----
    unsigned c32[2][4][2];
#pragma unroll
    for (int u = 0; u < 2; u++)
#pragma unroll
      for (int kc = 0; kc < 4; kc++) {
        float p0 = __builtin_amdgcn_exp2f(sacc[u][kc][0]);
        float p1 = __builtin_amdgcn_exp2f(sacc[u][kc][1]);
        float p2 = __builtin_amdgcn_exp2f(sacc[u][kc][2]);
        float p3 = __builtin_amdgcn_exp2f(sacc[u][kc][3]);
        lsum[u] += (p0 + p1) + (p2 + p3);
        c32[u][kc][0] = cvtpk_bf16(p0, p1);
        c32[u][kc][1] = cvtpk_bf16(p2, p3);
      }

    // ---- redistribute P^T to B-fragment layout (pure VALU permlane swaps) ----
    uint4 bfrag[2][2];
#pragma unroll
    for (int u = 0; u < 2; u++)
#pragma unroll
      for (int ka = 0; ka < 2; ka++) {
        unsigned x0 = c32[u][2 * ka][0],     x1 = c32[u][2 * ka][1];
        unsigned y0 = c32[u][2 * ka + 1][0], y1 = c32[u][2 * ka + 1][1];
        pl32swap(x0, y0);
        pl16swap(x0, y0);
        pl32swap(x1, y1);
        pl16swap(x1, y1);
        bfrag[u][ka] = (uint4){x0, x1, y0, y1};
      }

    // ---- O^T += V^T P^T (vf shared across both q-subtiles) ----
#pragma unroll
    for (int dc = 0; dc < 8; dc++) {
      uint4 vf0 = sV[cur][(dc * 16 + r) * 8 + (g ^ rx)];
      uint4 vf1 = sV[cur][(dc * 16 + r) * 8 + ((4 + g) ^ rx)];
      oacc[0][dc] = __builtin_amdgcn_mfma_f32_16x16x32_bf16(asbf8(vf0), asbf8(bfrag[0][0]), oacc[0][dc], 0, 0, 0);
      oacc[0][dc] = __builtin_amdgcn_mfma_f32_16x16x32_bf16(asbf8(vf1), asbf8(bfrag[0][1]), oacc[0][dc], 0, 0, 0);
      oacc[1][dc] = __builtin_amdgcn_mfma_f32_16x16x32_bf16(asbf8(vf0), asbf8(bfrag[1][0]), oacc[1][dc], 0, 0, 0);
      oacc[1][dc] = __builtin_amdgcn_mfma_f32_16x16x32_bf16(asbf8(vf1), asbf8(bfrag[1][1]), oacc[1][dc], 0, 0, 0);
    }

    __syncthreads();                           // drain prefetch; free cur buffers
    cur ^= 1;
  }

  // ---- reduce row-sums across the 4 g-groups ----
#pragma unroll
  for (int u = 0; u < 2; u++) {
    float v = lsum[u];
    v += __shfl_xor(v, 16);
    v += __shfl_xor(v, 32);
    lsum[u] = v;
  }

  // ---- epilogue: lane (r,g) holds O^T[d=16dc+4g+reg][q=qbase+u*16+r] ----
  if (outDirect) {
#pragma unroll
    for (int u = 0; u < 2; u++) {
      float inv = 1.f / lsum[u];
      int q = qbase + u * 16 + r;
#pragma unroll
      for (int dc = 0; dc < 8; dc++) {
        f32x4 o = oacc[u][dc] * inv;
        *(f32x4*)&outDirect[(size_t)q * DIM + dc * 16 + 4 * g] = o;
      }
    }
  } else {
#pragma unroll
    for (int u = 0; u < 2; u++) {
      int q = qbase + u * 16 + r;
      unsigned short* po = Opb + ((size_t)sp * NROWS + q) * DIM;
#pragma unroll
      for (int dc = 0; dc < 8; dc++) {
        uint2 pk;
        pk.x = cvtpk_bf16(oacc[u][dc][0], oacc[u][dc][1]);
        pk.y = cvtpk_bf16(oacc[u][dc][2], oacc[u][dc][3]);
        *(uint2*)&po[dc * 16 + 4 * g] = pk;
      }
      if (g == 0) Lp[(size_t)sp * NROWS + q] = lsum[u];
    }
  }
}

// ------------------------- KV-split combine (bf16 partials, plain sum) -------------------------
__global__ __launch_bounds__(256) void combine(
    const unsigned short* __restrict__ Opb, const float* __restrict__ Lp,
    float* __restrict__ out, int S)
{
  int gid = blockIdx.x * 256 + threadIdx.x;    // q*32 + d4
  int q = gid >> 5, d4 = gid & 31;
  float den = 0.f, n0 = 0.f, n1 = 0.f, n2 = 0.f, n3 = 0.f;
  for (int s = 0; s < S; s++) {
    den += Lp[(size_t)s * NROWS + q];
    ushort4v h = *(const ushort4v*)&Opb[((size_t)s * NROWS + q) * DIM + d4 * 4];
    n0 += __builtin_bit_cast(float, (unsigned)h[0] << 16);
    n1 += __builtin_bit_cast(float, (unsigned)h[1] << 16);
    n2 += __builtin_bit_cast(float, (unsigned)h[2] << 16);
    n3 += __builtin_bit_cast(float, (unsigned)h[3] << 16);
  }
  float inv = 1.f / den;
  float4 o = {n0 * inv, n1 * inv, n2 * inv, n3 * inv};
  *(float4*)&out[(size_t)q * DIM + d4 * 4] = o;
}

// ------------------------- launcher -------------------------
extern "C" void kernel_launch(void* const* d_in, const int* in_sizes, int n_in,
                              void* d_out, int out_size, void* d_ws, size_t ws_size,
                              hipStream_t stream)
{
  (void)in_sizes; (void)n_in; (void)out_size;
  const float* x = (const float*)d_in[0];
  const float* W = (const float*)d_in[1];
  const float* b = (const float*)d_in[2];
  float* out = (float*)d_out;
  char* ws = (char*)d_ws;

  unsigned short* Q  = (unsigned short*)ws;
  unsigned short* K  = Q + (size_t)NROWS * DIM;
  unsigned short* Vt = K + (size_t)NROWS * DIM;
  const size_t qkvB = (size_t)3 * NROWS * DIM * 2;

  auto need = [&](int S) {
    return qkvB + (size_t)S * NROWS * DIM * 2 + (size_t)S * NROWS * 4;
  };
  int S; bool direct = false;
  if      (ws_size >= need(8))  S = 8;
  else if (ws_size >= need(4))  S = 4;
  else if (ws_size >= need(2))  S = 2;
  else if (ws_size >= need(1))  S = 1;
  else { S = 1; direct = true; }

  unsigned short* Opb = (unsigned short*)(ws + qkvB);
  float* Lp = (float*)(Opb + (size_t)S * NROWS * DIM);

  qkv_proj<<<dim3(128, 6), 256, 0, stream>>>(x, W, b, Q, K, Vt);
  attn<<<dim3(64, S), 256, 0, stream>>>(Q, K, Vt, Opb, Lp,
                                        direct ? out : nullptr, NROWS / S);
  if (!direct) combine<<<1024, 256, 0, stream>>>(Opb, Lp, out, S);
}